// Round 1
// baseline (2042.585 us; speedup 1.0000x reference)
//
#include <hip/hip_runtime.h>

#define B_ 64
#define L_ 2048
#define G_ 512
#define F_ 3072
#define N_ 5632
#define NT_ 360448
#define EG_ 16384
#define E_ 1048576
#define EPS_ 1e-5f

// ---------------- CSR build (shared topology = first EG edges, graph 0) ----------------
__global__ void k_zero_cnt(int* cnt){ int i=blockIdx.x*256+threadIdx.x; if(i<N_) cnt[i]=0; }

__global__ void k_hist(const int* __restrict__ ei, int* __restrict__ cnt){
  int e=blockIdx.x*256+threadIdx.x;
  if(e<EG_) atomicAdd(&cnt[ei[E_+e]],1);
}

__global__ void k_scan(const int* __restrict__ cnt, int* __restrict__ off, int* __restrict__ cur){
  __shared__ int sm[1024];
  __shared__ int carry_s;
  int t=threadIdx.x;
  if(t==0) carry_s=0;
  __syncthreads();
  for(int base=0;base<N_;base+=1024){
    int i=base+t;
    int v=(i<N_)?cnt[i]:0;
    sm[t]=v; __syncthreads();
    for(int o=1;o<1024;o<<=1){
      int add=(t>=o)?sm[t-o]:0;
      __syncthreads();
      sm[t]+=add;
      __syncthreads();
    }
    int carry=carry_s;
    if(i<N_){ int ex=carry+sm[t]-v; off[i]=ex; cur[i]=ex; }
    __syncthreads();
    if(t==1023) carry_s=carry+sm[1023];
    __syncthreads();
  }
  if(t==0) off[N_]=carry_s;
}

__global__ void k_scatter(const int* __restrict__ ei, int* __restrict__ cur, int* __restrict__ srcs){
  int e=blockIdx.x*256+threadIdx.x;
  if(e<EG_){
    int d=ei[E_+e];
    int p=atomicAdd(&cur[d],1);
    srcs[p]=ei[e];
  }
}

// ---------------- encoder + fused LN (produces hn for layer 0) ----------------
__global__ __launch_bounds__(256) void k_enc(const float* __restrict__ x, float* __restrict__ hn,
    const float* __restrict__ ew, const float* __restrict__ eb,
    const float* __restrict__ lng, const float* __restrict__ lnb){
  int lane=threadIdx.x&63, wid=threadIdx.x>>6;
  int node0=blockIdx.x*32+wid*8;
  float w[7];
  #pragma unroll
  for(int k=0;k<7;k++) w[k]=ew[lane*7+k];
  float bias=eb[lane], gam=lng[lane], bet=lnb[lane];
  for(int t=0;t<8;t++){
    long n=node0+t;
    float acc=bias;
    #pragma unroll
    for(int k=0;k<7;k++) acc += x[n*7+k]*w[k];
    acc=fmaxf(acc,0.f);
    float s1=acc, s2=acc*acc;
    #pragma unroll
    for(int o=32;o>0;o>>=1){ s1+=__shfl_xor(s1,o,64); s2+=__shfl_xor(s2,o,64); }
    float mu=s1*(1.f/64.f);
    float var=s2*(1.f/64.f)-mu*mu;
    float inv=rsqrtf(var+EPS_);
    hn[n*64+lane]=(acc-mu)*inv*gam+bet;
  }
}

// ---------------- per-node GEMM: z = hn@Wrel^T (to z), r = hn@Wroot^T + b (in-place hn) ----------------
__global__ __launch_bounds__(256) void k_gemm(const float* __restrict__ wrel, const float* __restrict__ wroot,
    const float* __restrict__ brel, float* __restrict__ hn, float* __restrict__ z){
  long n=(long)blockIdx.x*256+threadIdx.x;   // exact grid: NT_/256
  float h[64];
  const float4* hp=(const float4*)(hn+n*64);
  #pragma unroll
  for(int c=0;c<16;c++){
    float4 v=hp[c];
    h[4*c]=v.x; h[4*c+1]=v.y; h[4*c+2]=v.z; h[4*c+3]=v.w;
  }
  float4* zp=(float4*)(z+n*64);
  float4* rp=(float4*)(hn+n*64);
  #pragma unroll 1
  for(int jc=0;jc<64;jc+=8){
    float az[8],ar[8];
    #pragma unroll
    for(int j=0;j<8;j++){ az[j]=0.f; ar[j]=brel[jc+j]; }
    #pragma unroll
    for(int k=0;k<64;k++){
      float hk=h[k];
      #pragma unroll
      for(int j=0;j<8;j++){
        az[j]=fmaf(wrel[(jc+j)*64+k],hk,az[j]);
        ar[j]=fmaf(wroot[(jc+j)*64+k],hk,ar[j]);
      }
    }
    zp[jc/4]   = make_float4(az[0],az[1],az[2],az[3]);
    zp[jc/4+1] = make_float4(az[4],az[5],az[6],az[7]);
    rp[jc/4]   = make_float4(ar[0],ar[1],ar[2],ar[3]);
    rp[jc/4+1] = make_float4(ar[4],ar[5],ar[6],ar[7]);
  }
}

// ---------------- gather-sum + relu + (fused next-layer LN) ----------------
__global__ __launch_bounds__(256) void k_agg(const float* __restrict__ z, float* __restrict__ hn,
    const int* __restrict__ off, const int* __restrict__ srcs,
    const float* __restrict__ lng, const float* __restrict__ lnb, int do_ln){
  int lane=threadIdx.x&63, wid=threadIdx.x>>6;
  int bid=blockIdx.x;
  const int P=N_/32;          // 176 blocks per graph
  int r8=bid/(8*P);           // round of 8 graphs -> keeps one graph per XCD's L2
  int rem=bid%(8*P);
  int xcd=rem&7;
  int j=rem>>3;
  int g=r8*8+xcd;
  int node0=j*32+wid*8;
  float gam=lng[lane], bet=lnb[lane];
  const float* zg = z + (long)g*N_*64;
  float* hg = hn + (long)g*N_*64;
  for(int t=0;t<8;t++){
    int d=node0+t;
    float acc=hg[(long)d*64+lane];          // r (root term + bias)
    int e0=off[d], e1=off[d+1];
    for(int e=e0;e<e1;e++){
      int s=srcs[e];
      acc+=zg[(long)s*64+lane];
    }
    acc=fmaxf(acc,0.f);
    if(do_ln){
      float s1=acc,s2=acc*acc;
      #pragma unroll
      for(int o=32;o>0;o>>=1){ s1+=__shfl_xor(s1,o,64); s2+=__shfl_xor(s2,o,64); }
      float mu=s1*(1.f/64.f);
      float var=s2*(1.f/64.f)-mu*mu;
      acc=(acc-mu)*rsqrtf(var+EPS_)*gam+bet;
    }
    hg[(long)d*64+lane]=acc;
  }
}

// ---------------- readouts ----------------
__global__ __launch_bounds__(256) void k_readout(const float* __restrict__ h, const int* __restrict__ idx,
    const float* __restrict__ w, const float* __restrict__ b1,
    float* __restrict__ out, float* __restrict__ outT, int M, int cols){
  int i=blockIdx.x*256+threadIdx.x;
  if(i>=M) return;
  long n=idx[i];
  const float4* hp=(const float4*)(h+n*64);
  float acc=b1[0];
  #pragma unroll
  for(int c=0;c<16;c++){
    float4 v=hp[c];
    acc += v.x*w[4*c] + v.y*w[4*c+1] + v.z*w[4*c+2] + v.w*w[4*c+3];
  }
  out[i]=acc;
  int bb=i/cols, cc=i%cols;
  outT[(long)cc*64+bb]=acc;
}

__global__ void k_md_init(const float* __restrict__ x, const int* __restrict__ loc, float* __restrict__ md){
  int i=blockIdx.x*256+threadIdx.x;
  if(i<B_*L_) md[i]=x[(long)loc[i]*7];
}

// wave = one location l, lane = graph b (B=64=wave width). seg splits the 3584-long mask row.
__global__ void k_md_acc(const float* __restrict__ gm, const float* __restrict__ lm,
    const float* __restrict__ pT, const float* __restrict__ fT, float* __restrict__ md){
  int lane=threadIdx.x&63, wid=threadIdx.x>>6;
  int l=blockIdx.x*4+wid;
  int seg=blockIdx.y;
  int c0=seg*448, c1=c0+448;
  float acc=0.f;
  for(int c=c0;c<c1;c++){
    float wm; const float* vs;
    if(c<G_){ wm=gm[(long)l*G_+c]; vs=&pT[(long)c*64]; }
    else    { int cf=c-G_; wm=lm[(long)l*F_+cf]; vs=&fT[(long)cf*64]; }
    if(wm!=0.f) acc += wm*vs[lane];      // wave-uniform skip: mask rows are sparse
  }
  atomicAdd(&md[(long)lane*L_+l], -acc);
}

extern "C" void kernel_launch(void* const* d_in, const int* in_sizes, int n_in,
                              void* d_out, int out_size, void* d_ws, size_t ws_size,
                              hipStream_t stream){
  const float* x    =(const float*)d_in[0];
  const int*   ei   =(const int*)d_in[1];
  const int*   prodi=(const int*)d_in[2];
  const int*   linei=(const int*)d_in[3];
  const int*   loci =(const int*)d_in[4];
  const float* ew   =(const float*)d_in[5];
  const float* eb   =(const float*)d_in[6];
  const float* lng  =(const float*)d_in[7];
  const float* lnb  =(const float*)d_in[8];
  const float* wrel =(const float*)d_in[9];
  const float* brel =(const float*)d_in[10];
  const float* wroot=(const float*)d_in[11];
  const float* pw   =(const float*)d_in[12];
  const float* pb   =(const float*)d_in[13];
  const float* fw   =(const float*)d_in[14];
  const float* fb   =(const float*)d_in[15];
  const float* gm   =(const float*)d_in[16];
  const float* lm   =(const float*)d_in[17];

  char* ws=(char*)d_ws;
  float* hn=(float*)ws;                               // NT*64 f32  (92.3 MB)
  float* z =(float*)(ws + (size_t)NT_*64*4);          // NT*64 f32  (92.3 MB)
  float* pT=(float*)(ws + (size_t)NT_*64*8);          // G*B
  float* fT=pT + (size_t)G_*B_;                       // F*B
  int* cnt =(int*)(fT + (size_t)F_*B_);
  int* off = cnt + N_;
  int* cur = off + (N_+1);
  int* srcs= cur + N_;

  float* outp =(float*)d_out;
  float* outf =outp + (size_t)B_*G_;
  float* outmd=outf + (size_t)B_*F_;

  k_zero_cnt<<<22,256,0,stream>>>(cnt);
  k_hist<<<64,256,0,stream>>>(ei,cnt);
  k_scan<<<1,1024,0,stream>>>(cnt,off,cur);
  k_scatter<<<64,256,0,stream>>>(ei,cur,srcs);
  k_enc<<<NT_/32,256,0,stream>>>(x,hn,ew,eb,lng,lnb);
  for(int i=0;i<4;i++){
    k_gemm<<<NT_/256,256,0,stream>>>(wrel+(size_t)i*4096, wroot+(size_t)i*4096, brel+(size_t)i*64, hn, z);
    k_agg<<<B_*(N_/32),256,0,stream>>>(z,hn,off,srcs,lng,lnb,(i<3)?1:0);
  }
  k_readout<<<(B_*G_)/256,256,0,stream>>>(hn,prodi,pw,pb,outp,pT,B_*G_,G_);
  k_readout<<<(B_*F_)/256,256,0,stream>>>(hn,linei,fw,fb,outf,fT,B_*F_,F_);
  k_md_init<<<(B_*L_)/256,256,0,stream>>>(x,loci,outmd);
  dim3 gmd(L_/4,8);
  k_md_acc<<<gmd,dim3(256),0,stream>>>(gm,lm,pT,fT,outmd);
}

// Round 2
// 1352.856 us; speedup vs baseline: 1.5098x; 1.5098x over previous
//
#include <hip/hip_runtime.h>

#define B_ 64
#define L_ 2048
#define G_ 512
#define F_ 3072
#define N_ 5632
#define NT_ 360448
#define EG_ 16384
#define E_ 1048576
#define EPS_ 1e-5f
#define MAXE_ 8192

// ---------------- CSR build (shared topology = first EG edges, graph 0) ----------------
__global__ void k_zero_cnt(int* cnt){ int i=blockIdx.x*256+threadIdx.x; if(i<N_) cnt[i]=0; }

__global__ void k_hist(const int* __restrict__ ei, int* __restrict__ cnt){
  int e=blockIdx.x*256+threadIdx.x;
  if(e<EG_) atomicAdd(&cnt[ei[E_+e]],1);
}

__global__ void k_scan(const int* __restrict__ cnt, int* __restrict__ off, int* __restrict__ cur){
  __shared__ int sm[1024];
  __shared__ int carry_s;
  int t=threadIdx.x;
  if(t==0) carry_s=0;
  __syncthreads();
  for(int base=0;base<N_;base+=1024){
    int i=base+t;
    int v=(i<N_)?cnt[i]:0;
    sm[t]=v; __syncthreads();
    for(int o=1;o<1024;o<<=1){
      int add=(t>=o)?sm[t-o]:0;
      __syncthreads();
      sm[t]+=add;
      __syncthreads();
    }
    int carry=carry_s;
    if(i<N_){ int ex=carry+sm[t]-v; off[i]=ex; cur[i]=ex; }
    __syncthreads();
    if(t==1023) carry_s=carry+sm[1023];
    __syncthreads();
  }
  if(t==0) off[N_]=carry_s;
}

__global__ void k_scatter(const int* __restrict__ ei, int* __restrict__ cur, int* __restrict__ srcs){
  int e=blockIdx.x*256+threadIdx.x;
  if(e<EG_){
    int d=ei[E_+e];
    int p=atomicAdd(&cur[d],1);
    srcs[p]=ei[e];
  }
}

// ---------------- encoder + fused LN (produces hn for layer 0) ----------------
__global__ __launch_bounds__(256) void k_enc(const float* __restrict__ x, float* __restrict__ hn,
    const float* __restrict__ ew, const float* __restrict__ eb,
    const float* __restrict__ lng, const float* __restrict__ lnb){
  int lane=threadIdx.x&63, wid=threadIdx.x>>6;
  int node0=blockIdx.x*32+wid*8;
  float w[7];
  #pragma unroll
  for(int k=0;k<7;k++) w[k]=ew[lane*7+k];
  float bias=eb[lane], gam=lng[lane], bet=lnb[lane];
  for(int t=0;t<8;t++){
    long n=node0+t;
    float acc=bias;
    #pragma unroll
    for(int k=0;k<7;k++) acc += x[n*7+k]*w[k];
    acc=fmaxf(acc,0.f);
    float s1=acc, s2=acc*acc;
    #pragma unroll
    for(int o=32;o>0;o>>=1){ s1+=__shfl_xor(s1,o,64); s2+=__shfl_xor(s2,o,64); }
    float mu=s1*(1.f/64.f);
    float var=s2*(1.f/64.f)-mu*mu;
    float inv=rsqrtf(var+EPS_);
    hn[n*64+lane]=(acc-mu)*inv*gam+bet;
  }
}

// ---------------- per-node GEMM, weight-resident: lane = output channel ----------------
// z[n][j] = sum_k wrel[j][k] h[n][k];  r[n][j] = sum_k wroot[j][k] h[n][k] + brel[j]
__global__ __launch_bounds__(256) void k_gemm(const float* __restrict__ wrel, const float* __restrict__ wroot,
    const float* __restrict__ brel, float* __restrict__ hn, float* __restrict__ z){
  int lane=threadIdx.x&63;
  int wv=blockIdx.x*4+(threadIdx.x>>6);     // NT_/64 waves total
  long n0=(long)wv*64;
  float wr[64], wo[64];
  const float4* wrp=(const float4*)(wrel+(long)lane*64);
  const float4* wop=(const float4*)(wroot+(long)lane*64);
  #pragma unroll
  for(int c=0;c<16;c++){
    float4 a=wrp[c]; wr[4*c]=a.x; wr[4*c+1]=a.y; wr[4*c+2]=a.z; wr[4*c+3]=a.w;
    float4 b=wop[c]; wo[4*c]=b.x; wo[4*c+1]=b.y; wo[4*c+2]=b.z; wo[4*c+3]=b.w;
  }
  float bias=brel[lane];
  float v=hn[n0*64+lane];
  for(int t=0;t<64;t++){
    long n=n0+t;
    float vn = (t<63) ? hn[(n+1)*64+lane] : 0.f;   // prefetch next row
    float az=0.f, ar=bias;
    #pragma unroll
    for(int k=0;k<64;k++){
      float hk=__int_as_float(__builtin_amdgcn_readlane(__float_as_int(v),k));
      az=fmaf(wr[k],hk,az);
      ar=fmaf(wo[k],hk,ar);
    }
    z[n*64+lane]=az;
    hn[n*64+lane]=ar;
    v=vn;
  }
}

// ---------------- gather-sum + relu + (fused next-layer LN) ----------------
__global__ __launch_bounds__(256) void k_agg(const float* __restrict__ z, float* __restrict__ hn,
    const int* __restrict__ off, const int* __restrict__ srcs,
    const float* __restrict__ lng, const float* __restrict__ lnb, int do_ln){
  int lane=threadIdx.x&63, wid=threadIdx.x>>6;
  int bid=blockIdx.x;
  const int P=N_/32;          // 176 blocks per graph
  int r8=bid/(8*P);           // round of 8 graphs -> one graph per XCD's L2
  int rem=bid%(8*P);
  int xcd=rem&7;
  int j=rem>>3;
  int g=r8*8+xcd;
  int node0=j*32+wid*8;
  float gam=lng[lane], bet=lnb[lane];
  const float* zg = z + (long)g*N_*64;
  float* hg = hn + (long)g*N_*64;
  for(int t=0;t<8;t++){
    int d=node0+t;
    float acc=hg[(long)d*64+lane];          // r (root term + bias)
    int e0=off[d], e1=off[d+1];
    for(int e=e0;e<e1;e++){
      int s=srcs[e];
      acc+=zg[(long)s*64+lane];
    }
    acc=fmaxf(acc,0.f);
    if(do_ln){
      float s1=acc,s2=acc*acc;
      #pragma unroll
      for(int o=32;o>0;o>>=1){ s1+=__shfl_xor(s1,o,64); s2+=__shfl_xor(s2,o,64); }
      float mu=s1*(1.f/64.f);
      float var=s2*(1.f/64.f)-mu*mu;
      acc=(acc-mu)*rsqrtf(var+EPS_)*gam+bet;
    }
    hg[(long)d*64+lane]=acc;
  }
}

// ---------------- readouts ----------------
__global__ __launch_bounds__(256) void k_readout(const float* __restrict__ h, const int* __restrict__ idx,
    const float* __restrict__ w, const float* __restrict__ b1,
    float* __restrict__ out, float* __restrict__ outT, int M, int cols){
  int i=blockIdx.x*256+threadIdx.x;
  if(i>=M) return;
  long n=idx[i];
  const float4* hp=(const float4*)(h+n*64);
  float acc=b1[0];
  #pragma unroll
  for(int c=0;c<16;c++){
    float4 v=hp[c];
    acc += v.x*w[4*c] + v.y*w[4*c+1] + v.z*w[4*c+2] + v.w*w[4*c+3];
  }
  out[i]=acc;
  int bb=i/cols, cc=i%cols;
  outT[(long)cc*64+bb]=acc;
}

// ---------------- sparse md pipeline ----------------
__global__ void k_md_zero(float* __restrict__ mdT, int* __restrict__ ecnt){
  int i=blockIdx.x*256+threadIdx.x;
  if(i<L_*64) mdT[i]=0.f;
  if(i==0) *ecnt=0;
}

// scan dense masks once, emit COO entries (l, col, w). col<G -> gen, else line.
__global__ void k_md_sparsify(const float* __restrict__ gm, const float* __restrict__ lm,
    int* __restrict__ ecnt, int4* __restrict__ ent){
  long i=(long)blockIdx.x*256+threadIdx.x;   // over L*(G+F)
  const long NG=(long)L_*G_;
  const long TOT=NG+(long)L_*F_;
  if(i>=TOT) return;
  float w; int l,c;
  if(i<NG){ w=gm[i]; l=(int)(i/G_); c=(int)(i%G_); }
  else    { long j=i-NG; w=lm[j]; l=(int)(j/F_); c=G_+(int)(j%F_); }
  if(w!=0.f){
    int p=atomicAdd(ecnt,1);
    if(p<MAXE_){ int4 e; e.x=l; e.y=c; e.z=__float_as_int(w); e.w=0; ent[p]=e; }
  }
}

// one wave per entry, lane = graph b; coalesced atomics into mdT[l][b]
__global__ __launch_bounds__(256) void k_md_scatter(const int4* __restrict__ ent, const int* __restrict__ ecnt,
    const float* __restrict__ pT, const float* __restrict__ fT, float* __restrict__ mdT){
  int wv=blockIdx.x*4+(threadIdx.x>>6);
  int lane=threadIdx.x&63;
  int nE=*ecnt; if(nE>MAXE_) nE=MAXE_;
  if(wv>=nE) return;
  int4 e=ent[wv];
  float w=__int_as_float(e.z);
  float val=(e.y<G_)? pT[(long)e.y*64+lane] : fT[(long)(e.y-G_)*64+lane];
  atomicAdd(&mdT[(long)e.x*64+lane], w*val);
}

__global__ void k_md_final(const float* __restrict__ x, const int* __restrict__ loc,
    const float* __restrict__ mdT, float* __restrict__ md){
  int i=blockIdx.x*256+threadIdx.x;   // i = b*L + l
  if(i<B_*L_){
    int b=i/L_, l=i%L_;
    md[i]=x[(long)loc[i]*7]-mdT[(long)l*64+b];
  }
}

extern "C" void kernel_launch(void* const* d_in, const int* in_sizes, int n_in,
                              void* d_out, int out_size, void* d_ws, size_t ws_size,
                              hipStream_t stream){
  const float* x    =(const float*)d_in[0];
  const int*   ei   =(const int*)d_in[1];
  const int*   prodi=(const int*)d_in[2];
  const int*   linei=(const int*)d_in[3];
  const int*   loci =(const int*)d_in[4];
  const float* ew   =(const float*)d_in[5];
  const float* eb   =(const float*)d_in[6];
  const float* lng  =(const float*)d_in[7];
  const float* lnb  =(const float*)d_in[8];
  const float* wrel =(const float*)d_in[9];
  const float* brel =(const float*)d_in[10];
  const float* wroot=(const float*)d_in[11];
  const float* pw   =(const float*)d_in[12];
  const float* pb   =(const float*)d_in[13];
  const float* fw   =(const float*)d_in[14];
  const float* fb   =(const float*)d_in[15];
  const float* gm   =(const float*)d_in[16];
  const float* lm   =(const float*)d_in[17];

  char* ws=(char*)d_ws;
  float* hn=(float*)ws;                               // NT*64 f32
  float* z =(float*)(ws + (size_t)NT_*64*4);          // NT*64 f32
  float* pT=(float*)(ws + (size_t)NT_*64*8);          // G*B
  float* fT=pT + (size_t)G_*B_;                       // F*B
  float* mdT=fT + (size_t)F_*B_;                      // L*64
  int* cnt =(int*)(mdT + (size_t)L_*64);
  int* off = cnt + N_;
  int* cur = off + (N_+1);
  int* srcs= cur + N_;
  int* ecnt= srcs + EG_;
  int4* ent=(int4*)(((size_t)(ecnt+1)+15)&~(size_t)15);

  float* outp =(float*)d_out;
  float* outf =outp + (size_t)B_*G_;
  float* outmd=outf + (size_t)B_*F_;

  k_zero_cnt<<<22,256,0,stream>>>(cnt);
  k_hist<<<64,256,0,stream>>>(ei,cnt);
  k_scan<<<1,1024,0,stream>>>(cnt,off,cur);
  k_scatter<<<64,256,0,stream>>>(ei,cur,srcs);
  k_md_zero<<<512,256,0,stream>>>(mdT,ecnt);
  {
    long tot=(long)L_*(G_+F_);
    int blocks=(int)((tot+255)/256);
    k_md_sparsify<<<blocks,256,0,stream>>>(gm,lm,ecnt,ent);
  }
  k_enc<<<NT_/32,256,0,stream>>>(x,hn,ew,eb,lng,lnb);
  for(int i=0;i<4;i++){
    k_gemm<<<NT_/256,256,0,stream>>>(wrel+(size_t)i*4096, wroot+(size_t)i*4096, brel+(size_t)i*64, hn, z);
    k_agg<<<B_*(N_/32),256,0,stream>>>(z,hn,off,srcs,lng,lnb,(i<3)?1:0);
  }
  k_readout<<<(B_*G_)/256,256,0,stream>>>(hn,prodi,pw,pb,outp,pT,B_*G_,G_);
  k_readout<<<(B_*F_)/256,256,0,stream>>>(hn,linei,fw,fb,outf,fT,B_*F_,F_);
  k_md_scatter<<<MAXE_/4,256,0,stream>>>(ent,ecnt,pT,fT,mdT);
  k_md_final<<<(B_*L_)/256,256,0,stream>>>(x,loci,mdT,outmd);
}

// Round 3
// 762.646 us; speedup vs baseline: 2.6783x; 1.7739x over previous
//
#include <hip/hip_runtime.h>

#define B_ 64
#define L_ 2048
#define G_ 512
#define F_ 3072
#define N_ 5632
#define NT_ 360448
#define EG_ 16384
#define E_ 1048576
#define EPS_ 1e-5f
#define MAXE_ 8192

typedef __attribute__((ext_vector_type(8))) short bf8v;
typedef __attribute__((ext_vector_type(4))) float f4v;

__device__ __forceinline__ unsigned short f2bf(float f){
  unsigned int u=__float_as_uint(f);
  unsigned int r=(u + 0x7fffu + ((u>>16)&1u))>>16;
  return (unsigned short)r;
}
__device__ __forceinline__ float bf2f(unsigned short h){
  return __uint_as_float(((unsigned int)h)<<16);
}

// ---------------- CSR build (shared topology = first EG edges, graph 0) ----------------
__global__ void k_zero_cnt(int* cnt){ int i=blockIdx.x*256+threadIdx.x; if(i<N_) cnt[i]=0; }

__global__ void k_hist(const int* __restrict__ ei, int* __restrict__ cnt){
  int e=blockIdx.x*256+threadIdx.x;
  if(e<EG_) atomicAdd(&cnt[ei[E_+e]],1);
}

__global__ void k_scan(const int* __restrict__ cnt, int* __restrict__ off, int* __restrict__ cur){
  __shared__ int sm[1024];
  __shared__ int carry_s;
  int t=threadIdx.x;
  if(t==0) carry_s=0;
  __syncthreads();
  for(int base=0;base<N_;base+=1024){
    int i=base+t;
    int v=(i<N_)?cnt[i]:0;
    sm[t]=v; __syncthreads();
    for(int o=1;o<1024;o<<=1){
      int add=(t>=o)?sm[t-o]:0;
      __syncthreads();
      sm[t]+=add;
      __syncthreads();
    }
    int carry=carry_s;
    if(i<N_){ int ex=carry+sm[t]-v; off[i]=ex; cur[i]=ex; }
    __syncthreads();
    if(t==1023) carry_s=carry+sm[1023];
    __syncthreads();
  }
  if(t==0) off[N_]=carry_s;
}

__global__ void k_scatter(const int* __restrict__ ei, int* __restrict__ cur, int* __restrict__ srcs){
  int e=blockIdx.x*256+threadIdx.x;
  if(e<EG_){
    int d=ei[E_+e];
    int p=atomicAdd(&cur[d],1);
    srcs[p]=ei[e];
  }
}

// ---------------- weight prep: wcat[l][n][128] bf16 = [wrel[l][n][:] | wroot[l][n][:]] ----------------
__global__ void k_wprep(const float* __restrict__ wrel, const float* __restrict__ wroot,
                        unsigned short* __restrict__ wcat){
  int i=blockIdx.x*256+threadIdx.x;   // 4*64*128 = 32768
  if(i>=32768) return;
  int l=i>>13; int rest=i&8191; int n=rest>>7; int k=rest&127;
  float v=(k<64)? wrel[((long)l*64+n)*64+k] : wroot[((long)l*64+n)*64+(k-64)];
  wcat[i]=f2bf(v);
}

// ---------------- encoder + fused LN (produces hn bf16 for layer 0) ----------------
__global__ __launch_bounds__(256) void k_enc(const float* __restrict__ x, unsigned short* __restrict__ hn,
    const float* __restrict__ ew, const float* __restrict__ eb,
    const float* __restrict__ lng, const float* __restrict__ lnb){
  int lane=threadIdx.x&63, wid=threadIdx.x>>6;
  int node0=blockIdx.x*32+wid*8;
  float w[7];
  #pragma unroll
  for(int k=0;k<7;k++) w[k]=ew[lane*7+k];
  float bias=eb[lane], gam=lng[lane], bet=lnb[lane];
  for(int t=0;t<8;t++){
    long n=node0+t;
    float acc=bias;
    #pragma unroll
    for(int k=0;k<7;k++) acc += x[n*7+k]*w[k];
    acc=fmaxf(acc,0.f);
    float s1=acc, s2=acc*acc;
    #pragma unroll
    for(int o=32;o>0;o>>=1){ s1+=__shfl_xor(s1,o,64); s2+=__shfl_xor(s2,o,64); }
    float mu=s1*(1.f/64.f);
    float var=s2*(1.f/64.f)-mu*mu;
    float inv=rsqrtf(var+EPS_);
    hn[n*64+lane]=f2bf((acc-mu)*inv*gam+bet);
  }
}

// ---------------- gather-sum: a[d] = sum_{s in N(d)} hn[s]  (bf16 in/out, fp32 acc) ----------------
__global__ __launch_bounds__(256) void k_agg2(const unsigned short* __restrict__ hn,
    unsigned short* __restrict__ a, const int* __restrict__ off, const int* __restrict__ srcs){
  int lane=threadIdx.x&63, wid=threadIdx.x>>6;
  int bid=blockIdx.x;
  const int P=N_/32;          // 176 blocks per graph
  int r8=bid/(8*P);           // one graph per XCD's L2
  int rem=bid%(8*P);
  int xcd=rem&7;
  int j=rem>>3;
  int g=r8*8+xcd;
  int node0=j*32+wid*8;
  int c2=lane&31, eh=lane>>5;          // channel pair + edge-half
  const unsigned short* hg = hn + (long)g*N_*64;
  unsigned short* ag = a + (long)g*N_*64;
  for(int t=0;t<8;t++){
    int d=node0+t;
    int e0=off[d], e1=off[d+1];
    float ax=0.f, ay=0.f;
    for(int e=e0+eh; e<e1; e+=2){
      int s=srcs[e];
      ushort2 u=*(const ushort2*)(hg + (long)s*64 + 2*c2);
      ax+=bf2f(u.x); ay+=bf2f(u.y);
    }
    ax+=__shfl_xor(ax,32,64);
    ay+=__shfl_xor(ay,32,64);
    if(eh==0){
      ushort2 o; o.x=f2bf(ax); o.y=f2bf(ay);
      *(ushort2*)(ag + (long)d*64 + 2*c2)=o;
    }
  }
}

// ---------------- MFMA GEMM: hn' = relu([a|hn] @ Wcat^T + b), optional fused LN ----------------
// wave = 16 nodes x 64 channels; 4 accumulator tiles (16ch each) x 4 K-steps (K=128)
__global__ __launch_bounds__(256) void k_mm(const unsigned short* __restrict__ a,
    unsigned short* __restrict__ hn, const unsigned short* __restrict__ wcat,
    const float* __restrict__ brel, const float* __restrict__ lng, const float* __restrict__ lnb,
    int do_ln){
  int tid=threadIdx.x;
  int w=tid>>6, lane=tid&63;
  int m=lane&15, quad=lane>>4;
  long nodeA=(long)blockIdx.x*64 + w*16 + m;
  const unsigned short* arow=a + nodeA*64;
  const unsigned short* hrow=hn + nodeA*64;
  bf8v af0=*(const bf8v*)(arow + quad*8);
  bf8v af1=*(const bf8v*)(arow + 32 + quad*8);
  bf8v af2=*(const bf8v*)(hrow + quad*8);
  bf8v af3=*(const bf8v*)(hrow + 32 + quad*8);
  f4v acc[4];
  float bias_nt[4], g_nt[4], b_nt[4];
  #pragma unroll
  for(int nt=0;nt<4;nt++){
    int c=nt*16+m;
    bias_nt[nt]=brel[c];
    g_nt[nt]=lng[c]; b_nt[nt]=lnb[c];
    acc[nt]=(f4v){0.f,0.f,0.f,0.f};
    const unsigned short* wrow=wcat + (long)c*128 + quad*8;
    bf8v b0=*(const bf8v*)(wrow);
    bf8v b1=*(const bf8v*)(wrow+32);
    bf8v b2=*(const bf8v*)(wrow+64);
    bf8v b3=*(const bf8v*)(wrow+96);
    acc[nt]=__builtin_amdgcn_mfma_f32_16x16x32_bf16(af0,b0,acc[nt],0,0,0);
    acc[nt]=__builtin_amdgcn_mfma_f32_16x16x32_bf16(af1,b1,acc[nt],0,0,0);
    acc[nt]=__builtin_amdgcn_mfma_f32_16x16x32_bf16(af2,b2,acc[nt],0,0,0);
    acc[nt]=__builtin_amdgcn_mfma_f32_16x16x32_bf16(af3,b3,acc[nt],0,0,0);
  }
  // epilogue: bias + relu (+ LN over the 64 channels of each row)
  float v[4][4];
  #pragma unroll
  for(int nt=0;nt<4;nt++)
    #pragma unroll
    for(int r=0;r<4;r++)
      v[nt][r]=fmaxf(acc[nt][r]+bias_nt[nt],0.f);
  if(do_ln){
    #pragma unroll
    for(int r=0;r<4;r++){
      float rs=v[0][r]+v[1][r]+v[2][r]+v[3][r];
      float rss=v[0][r]*v[0][r]+v[1][r]*v[1][r]+v[2][r]*v[2][r]+v[3][r]*v[3][r];
      #pragma unroll
      for(int o=1;o<16;o<<=1){ rs+=__shfl_xor(rs,o,64); rss+=__shfl_xor(rss,o,64); }
      float mu=rs*(1.f/64.f);
      float var=rss*(1.f/64.f)-mu*mu;
      float inv=rsqrtf(var+EPS_);
      #pragma unroll
      for(int nt=0;nt<4;nt++) v[nt][r]=(v[nt][r]-mu)*inv*g_nt[nt]+b_nt[nt];
    }
  }
  long rowbase=(long)blockIdx.x*64 + w*16 + quad*4;
  #pragma unroll
  for(int r=0;r<4;r++){
    unsigned short* out=hn + (rowbase+r)*64;
    #pragma unroll
    for(int nt=0;nt<4;nt++) out[nt*16+m]=f2bf(v[nt][r]);
  }
}

// ---------------- readouts (bf16 h) ----------------
__global__ __launch_bounds__(256) void k_readout(const unsigned short* __restrict__ h, const int* __restrict__ idx,
    const float* __restrict__ w, const float* __restrict__ b1,
    float* __restrict__ out, float* __restrict__ outT, int M, int cols){
  int i=blockIdx.x*256+threadIdx.x;
  if(i>=M) return;
  long n=idx[i];
  const uint4* hp=(const uint4*)(h+n*64);
  float acc=b1[0];
  #pragma unroll
  for(int c=0;c<8;c++){
    uint4 u=hp[c];
    unsigned int uu[4]={u.x,u.y,u.z,u.w};
    #pragma unroll
    for(int q=0;q<4;q++){
      float lo=__uint_as_float(uu[q]<<16);
      float hi=__uint_as_float(uu[q]&0xffff0000u);
      acc += lo*w[c*8+2*q] + hi*w[c*8+2*q+1];
    }
  }
  out[i]=acc;
  int bb=i/cols, cc=i%cols;
  outT[(long)cc*64+bb]=acc;
}

// ---------------- sparse md pipeline ----------------
__global__ void k_md_zero(float* __restrict__ mdT, int* __restrict__ ecnt){
  int i=blockIdx.x*256+threadIdx.x;
  if(i<L_*64) mdT[i]=0.f;
  if(i==0) *ecnt=0;
}

__global__ void k_md_sparsify(const float* __restrict__ gm, const float* __restrict__ lm,
    int* __restrict__ ecnt, int4* __restrict__ ent){
  long i=(long)blockIdx.x*256+threadIdx.x;   // over L*(G+F)
  const long NG=(long)L_*G_;
  const long TOT=NG+(long)L_*F_;
  if(i>=TOT) return;
  float w; int l,c;
  if(i<NG){ w=gm[i]; l=(int)(i/G_); c=(int)(i%G_); }
  else    { long j=i-NG; w=lm[j]; l=(int)(j/F_); c=G_+(int)(j%F_); }
  if(w!=0.f){
    int p=atomicAdd(ecnt,1);
    if(p<MAXE_){ int4 e; e.x=l; e.y=c; e.z=__float_as_int(w); e.w=0; ent[p]=e; }
  }
}

__global__ __launch_bounds__(256) void k_md_scatter(const int4* __restrict__ ent, const int* __restrict__ ecnt,
    const float* __restrict__ pT, const float* __restrict__ fT, float* __restrict__ mdT){
  int wv=blockIdx.x*4+(threadIdx.x>>6);
  int lane=threadIdx.x&63;
  int nE=*ecnt; if(nE>MAXE_) nE=MAXE_;
  if(wv>=nE) return;
  int4 e=ent[wv];
  float w=__int_as_float(e.z);
  float val=(e.y<G_)? pT[(long)e.y*64+lane] : fT[(long)(e.y-G_)*64+lane];
  atomicAdd(&mdT[(long)e.x*64+lane], w*val);
}

__global__ void k_md_final(const float* __restrict__ x, const int* __restrict__ loc,
    const float* __restrict__ mdT, float* __restrict__ md){
  int i=blockIdx.x*256+threadIdx.x;   // i = b*L + l
  if(i<B_*L_){
    int b=i/L_, l=i%L_;
    md[i]=x[(long)loc[i]*7]-mdT[(long)l*64+b];
  }
}

extern "C" void kernel_launch(void* const* d_in, const int* in_sizes, int n_in,
                              void* d_out, int out_size, void* d_ws, size_t ws_size,
                              hipStream_t stream){
  const float* x    =(const float*)d_in[0];
  const int*   ei   =(const int*)d_in[1];
  const int*   prodi=(const int*)d_in[2];
  const int*   linei=(const int*)d_in[3];
  const int*   loci =(const int*)d_in[4];
  const float* ew   =(const float*)d_in[5];
  const float* eb   =(const float*)d_in[6];
  const float* lng  =(const float*)d_in[7];
  const float* lnb  =(const float*)d_in[8];
  const float* wrel =(const float*)d_in[9];
  const float* brel =(const float*)d_in[10];
  const float* wroot=(const float*)d_in[11];
  const float* pw   =(const float*)d_in[12];
  const float* pb   =(const float*)d_in[13];
  const float* fw   =(const float*)d_in[14];
  const float* fb   =(const float*)d_in[15];
  const float* gm   =(const float*)d_in[16];
  const float* lm   =(const float*)d_in[17];

  char* ws=(char*)d_ws;
  unsigned short* hn  =(unsigned short*)ws;                        // NT*64 bf16 (46.1 MB)
  unsigned short* a   =hn + (size_t)NT_*64;                        // NT*64 bf16 (46.1 MB)
  unsigned short* wcat=a + (size_t)NT_*64;                         // 32768 bf16 (64 KB)
  float* pT =(float*)(wcat + 32768);                               // G*B
  float* fT =pT + (size_t)G_*B_;                                   // F*B
  float* mdT=fT + (size_t)F_*B_;                                   // L*64
  int* cnt =(int*)(mdT + (size_t)L_*64);
  int* off = cnt + N_;
  int* cur = off + (N_+1);
  int* srcs= cur + N_;
  int* ecnt= srcs + EG_;
  int4* ent=(int4*)(((size_t)(ecnt+1)+15)&~(size_t)15);

  float* outp =(float*)d_out;
  float* outf =outp + (size_t)B_*G_;
  float* outmd=outf + (size_t)B_*F_;

  k_zero_cnt<<<22,256,0,stream>>>(cnt);
  k_hist<<<64,256,0,stream>>>(ei,cnt);
  k_scan<<<1,1024,0,stream>>>(cnt,off,cur);
  k_scatter<<<64,256,0,stream>>>(ei,cur,srcs);
  k_wprep<<<128,256,0,stream>>>(wrel,wroot,wcat);
  k_md_zero<<<512,256,0,stream>>>(mdT,ecnt);
  {
    long tot=(long)L_*(G_+F_);
    int blocks=(int)((tot+255)/256);
    k_md_sparsify<<<blocks,256,0,stream>>>(gm,lm,ecnt,ent);
  }
  k_enc<<<NT_/32,256,0,stream>>>(x,hn,ew,eb,lng,lnb);
  for(int i=0;i<4;i++){
    k_agg2<<<B_*(N_/32),256,0,stream>>>(hn,a,off,srcs);
    k_mm<<<NT_/64,256,0,stream>>>(a,hn,wcat+(size_t)i*8192,brel+(size_t)i*64,lng,lnb,(i<3)?1:0);
  }
  k_readout<<<(B_*G_)/256,256,0,stream>>>(hn,prodi,pw,pb,outp,pT,B_*G_,G_);
  k_readout<<<(B_*F_)/256,256,0,stream>>>(hn,linei,fw,fb,outf,fT,B_*F_,F_);
  k_md_scatter<<<MAXE_/4,256,0,stream>>>(ent,ecnt,pT,fT,mdT);
  k_md_final<<<(B_*L_)/256,256,0,stream>>>(x,loci,mdT,outmd);
}

// Round 4
// 742.075 us; speedup vs baseline: 2.7525x; 1.0277x over previous
//
#include <hip/hip_runtime.h>

#define B_ 64
#define L_ 2048
#define G_ 512
#define F_ 3072
#define N_ 5632
#define NT_ 360448
#define EG_ 16384
#define E_ 1048576
#define EPS_ 1e-5f
#define MAXE_ 8192
#define PAD_ 136   // LDS row stride (ushorts): 64 agg | 64 root | 8 pad

typedef __attribute__((ext_vector_type(8))) short bf8v;
typedef __attribute__((ext_vector_type(4))) float f4v;

__device__ __forceinline__ unsigned short f2bf(float f){
  unsigned int u=__float_as_uint(f);
  unsigned int r=(u + 0x7fffu + ((u>>16)&1u))>>16;
  return (unsigned short)r;
}
__device__ __forceinline__ float bf2f(unsigned short h){
  return __uint_as_float(((unsigned int)h)<<16);
}

// ---------------- fused init: cnt=0, mdT=0, ecnt=0, wcat build ----------------
__global__ void k_init(int* __restrict__ cnt, float* __restrict__ mdT, int* __restrict__ ecnt,
                       const float* __restrict__ wrel, const float* __restrict__ wroot,
                       unsigned short* __restrict__ wcat){
  int i=blockIdx.x*256+threadIdx.x;      // grid covers L_*64 = 131072
  if(i<L_*64) mdT[i]=0.f;
  if(i<N_) cnt[i]=0;
  if(i==0) *ecnt=0;
  if(i<32768){
    int l=i>>13; int rest=i&8191; int n=rest>>7; int k=rest&127;
    float v=(k<64)? wrel[((long)l*64+n)*64+k] : wroot[((long)l*64+n)*64+(k-64)];
    wcat[i]=f2bf(v);
  }
}

// ---------------- CSR build (shared topology = first EG edges, graph 0) ----------------
__global__ void k_hist(const int* __restrict__ ei, int* __restrict__ cnt){
  int e=blockIdx.x*256+threadIdx.x;
  if(e<EG_) atomicAdd(&cnt[ei[E_+e]],1);
}

__global__ void k_scan(const int* __restrict__ cnt, int* __restrict__ off, int* __restrict__ cur){
  __shared__ int sm[1024];
  __shared__ int carry_s;
  int t=threadIdx.x;
  if(t==0) carry_s=0;
  __syncthreads();
  for(int base=0;base<N_;base+=1024){
    int i=base+t;
    int v=(i<N_)?cnt[i]:0;
    sm[t]=v; __syncthreads();
    for(int o=1;o<1024;o<<=1){
      int add=(t>=o)?sm[t-o]:0;
      __syncthreads();
      sm[t]+=add;
      __syncthreads();
    }
    int carry=carry_s;
    if(i<N_){ int ex=carry+sm[t]-v; off[i]=ex; cur[i]=ex; }
    __syncthreads();
    if(t==1023) carry_s=carry+sm[1023];
    __syncthreads();
  }
  if(t==0) off[N_]=carry_s;
}

__global__ void k_scatter(const int* __restrict__ ei, int* __restrict__ cur, int* __restrict__ srcs){
  int e=blockIdx.x*256+threadIdx.x;
  if(e<EG_){
    int d=ei[E_+e];
    int p=atomicAdd(&cur[d],1);
    srcs[p]=ei[e];
  }
}

// ---------------- encoder + fused LN (produces hnA bf16 for layer 0) ----------------
__global__ __launch_bounds__(256) void k_enc(const float* __restrict__ x, unsigned short* __restrict__ hn,
    const float* __restrict__ ew, const float* __restrict__ eb,
    const float* __restrict__ lng, const float* __restrict__ lnb){
  int lane=threadIdx.x&63, wid=threadIdx.x>>6;
  int node0=blockIdx.x*32+wid*8;
  float w[7];
  #pragma unroll
  for(int k=0;k<7;k++) w[k]=ew[lane*7+k];
  float bias=eb[lane], gam=lng[lane], bet=lnb[lane];
  for(int t=0;t<8;t++){
    long n=node0+t;
    float acc=bias;
    #pragma unroll
    for(int k=0;k<7;k++) acc += x[n*7+k]*w[k];
    acc=fmaxf(acc,0.f);
    float s1=acc, s2=acc*acc;
    #pragma unroll
    for(int o=32;o>0;o>>=1){ s1+=__shfl_xor(s1,o,64); s2+=__shfl_xor(s2,o,64); }
    float mu=s1*(1.f/64.f);
    float var=s2*(1.f/64.f)-mu*mu;
    float inv=rsqrtf(var+EPS_);
    hn[n*64+lane]=f2bf((acc-mu)*inv*gam+bet);
  }
}

// ---------------- fused layer: gather-sum -> LDS -> MFMA -> bias/relu/LN -> hd ----------------
// block = 64 nodes of one graph; reads hs, writes hd (ping-pong, no in-place race)
__global__ __launch_bounds__(256) void k_layer(const unsigned short* __restrict__ hs,
    unsigned short* __restrict__ hd, const int* __restrict__ off, const int* __restrict__ srcs,
    const unsigned short* __restrict__ wcat, const float* __restrict__ brel,
    const float* __restrict__ lng, const float* __restrict__ lnb, int do_ln){
  __shared__ unsigned short cat[64*PAD_];
  int tid=threadIdx.x;
  int w=tid>>6, lane=tid&63;
  int bid=blockIdx.x;
  const int P=N_/64;                 // 88 blocks per graph
  int r8=bid/(8*P), rem=bid%(8*P);
  int xcd=rem&7, j=rem>>3, g=r8*8+xcd;   // one graph per XCD's L2
  const unsigned short* hg = hs + (long)g*N_*64;
  int c2=lane&31, eh=lane>>5;        // channel-pair + edge-half
  int nodebase=j*64;
  // ---- phase 1: aggregate neighbors + copy root row into LDS concat tile ----
  for(int t=0;t<16;t++){
    int dl=w*16+t;
    int d=nodebase+dl;
    int e0=off[d], e1=off[d+1];
    float ax=0.f, ay=0.f;
    for(int e=e0+eh; e<e1; e+=2){
      int s=srcs[e];
      ushort2 u=*(const ushort2*)(hg + (long)s*64 + 2*c2);
      ax+=bf2f(u.x); ay+=bf2f(u.y);
    }
    ax+=__shfl_xor(ax,32,64);
    ay+=__shfl_xor(ay,32,64);
    ushort2 rp=*(const ushort2*)(hg + (long)d*64 + 2*c2);   // root pair (broadcast across halves)
    ushort2 ov;
    if(eh==0){ ov.x=f2bf(ax); ov.y=f2bf(ay); } else ov=rp;
    *(ushort2*)(&cat[dl*PAD_ + eh*64 + 2*c2]) = ov;
  }
  __syncthreads();
  // ---- phase 2: MFMA [agg|root] @ Wcat^T, fused epilogue ----
  int m=lane&15, quad=lane>>4;
  const unsigned short* arow=&cat[(w*16+m)*PAD_];
  bf8v af0=*(const bf8v*)(arow + quad*8);
  bf8v af1=*(const bf8v*)(arow + 32 + quad*8);
  bf8v af2=*(const bf8v*)(arow + 64 + quad*8);
  bf8v af3=*(const bf8v*)(arow + 96 + quad*8);
  f4v acc[4];
  float bias_nt[4], g_nt[4], b_nt[4];
  #pragma unroll
  for(int nt=0;nt<4;nt++){
    int c=nt*16+m;
    bias_nt[nt]=brel[c];
    g_nt[nt]=lng[c]; b_nt[nt]=lnb[c];
    acc[nt]=(f4v){0.f,0.f,0.f,0.f};
    const unsigned short* wrow=wcat + (long)c*128 + quad*8;
    bf8v b0=*(const bf8v*)(wrow);
    bf8v b1=*(const bf8v*)(wrow+32);
    bf8v b2=*(const bf8v*)(wrow+64);
    bf8v b3=*(const bf8v*)(wrow+96);
    acc[nt]=__builtin_amdgcn_mfma_f32_16x16x32_bf16(af0,b0,acc[nt],0,0,0);
    acc[nt]=__builtin_amdgcn_mfma_f32_16x16x32_bf16(af1,b1,acc[nt],0,0,0);
    acc[nt]=__builtin_amdgcn_mfma_f32_16x16x32_bf16(af2,b2,acc[nt],0,0,0);
    acc[nt]=__builtin_amdgcn_mfma_f32_16x16x32_bf16(af3,b3,acc[nt],0,0,0);
  }
  float v[4][4];
  #pragma unroll
  for(int nt=0;nt<4;nt++)
    #pragma unroll
    for(int r=0;r<4;r++)
      v[nt][r]=fmaxf(acc[nt][r]+bias_nt[nt],0.f);
  if(do_ln){
    #pragma unroll
    for(int r=0;r<4;r++){
      float rs=v[0][r]+v[1][r]+v[2][r]+v[3][r];
      float rss=v[0][r]*v[0][r]+v[1][r]*v[1][r]+v[2][r]*v[2][r]+v[3][r]*v[3][r];
      #pragma unroll
      for(int o=1;o<16;o<<=1){ rs+=__shfl_xor(rs,o,64); rss+=__shfl_xor(rss,o,64); }
      float mu=rs*(1.f/64.f);
      float var=rss*(1.f/64.f)-mu*mu;
      float inv=rsqrtf(var+EPS_);
      #pragma unroll
      for(int nt=0;nt<4;nt++) v[nt][r]=(v[nt][r]-mu)*inv*g_nt[nt]+b_nt[nt];
    }
  }
  long rowbase=(long)g*N_ + nodebase + w*16 + quad*4;
  #pragma unroll
  for(int r=0;r<4;r++){
    unsigned short* out=hd + (rowbase+r)*64;
    #pragma unroll
    for(int nt=0;nt<4;nt++) out[nt*16+m]=f2bf(v[nt][r]);
  }
}

// ---------------- readouts (bf16 h) ----------------
__global__ __launch_bounds__(256) void k_readout(const unsigned short* __restrict__ h, const int* __restrict__ idx,
    const float* __restrict__ w, const float* __restrict__ b1,
    float* __restrict__ out, float* __restrict__ outT, int M, int cols){
  int i=blockIdx.x*256+threadIdx.x;
  if(i>=M) return;
  long n=idx[i];
  const uint4* hp=(const uint4*)(h+n*64);
  float acc=b1[0];
  #pragma unroll
  for(int c=0;c<8;c++){
    uint4 u=hp[c];
    unsigned int uu[4]={u.x,u.y,u.z,u.w};
    #pragma unroll
    for(int q=0;q<4;q++){
      float lo=__uint_as_float(uu[q]<<16);
      float hi=__uint_as_float(uu[q]&0xffff0000u);
      acc += lo*w[c*8+2*q] + hi*w[c*8+2*q+1];
    }
  }
  out[i]=acc;
  int bb=i/cols, cc=i%cols;
  outT[(long)cc*64+bb]=acc;
}

// ---------------- sparse md pipeline ----------------
// grid-stride float4 scan of the dense masks, emit COO entries (l, col, w)
__global__ __launch_bounds__(256) void k_md_sparsify(const float* __restrict__ gm, const float* __restrict__ lm,
    int* __restrict__ ecnt, int4* __restrict__ ent){
  const int NG4=(L_*G_)/4;          // 262144
  const int NL4=(L_*F_)/4;         // 1572864
  int stride=gridDim.x*256;
  for(int i=blockIdx.x*256+threadIdx.x; i<NG4; i+=stride){
    float4 v=((const float4*)gm)[i];
    float c4[4]={v.x,v.y,v.z,v.w};
    #pragma unroll
    for(int q=0;q<4;q++) if(c4[q]!=0.f){
      int fi=4*i+q;
      int p=atomicAdd(ecnt,1);
      if(p<MAXE_){ int4 e; e.x=fi/G_; e.y=fi%G_; e.z=__float_as_int(c4[q]); e.w=0; ent[p]=e; }
    }
  }
  for(int i=blockIdx.x*256+threadIdx.x; i<NL4; i+=stride){
    float4 v=((const float4*)lm)[i];
    float c4[4]={v.x,v.y,v.z,v.w};
    #pragma unroll
    for(int q=0;q<4;q++) if(c4[q]!=0.f){
      int fi=4*i+q;
      int p=atomicAdd(ecnt,1);
      if(p<MAXE_){ int4 e; e.x=fi/F_; e.y=G_+fi%F_; e.z=__float_as_int(c4[q]); e.w=0; ent[p]=e; }
    }
  }
}

__global__ __launch_bounds__(256) void k_md_scatter(const int4* __restrict__ ent, const int* __restrict__ ecnt,
    const float* __restrict__ pT, const float* __restrict__ fT, float* __restrict__ mdT){
  int wv=blockIdx.x*4+(threadIdx.x>>6);
  int lane=threadIdx.x&63;
  int nE=*ecnt; if(nE>MAXE_) nE=MAXE_;
  if(wv>=nE) return;
  int4 e=ent[wv];
  float w=__int_as_float(e.z);
  float val=(e.y<G_)? pT[(long)e.y*64+lane] : fT[(long)(e.y-G_)*64+lane];
  atomicAdd(&mdT[(long)e.x*64+lane], w*val);
}

__global__ void k_md_final(const float* __restrict__ x, const int* __restrict__ loc,
    const float* __restrict__ mdT, float* __restrict__ md){
  int i=blockIdx.x*256+threadIdx.x;   // i = b*L + l
  if(i<B_*L_){
    int b=i/L_, l=i%L_;
    md[i]=x[(long)loc[i]*7]-mdT[(long)l*64+b];
  }
}

extern "C" void kernel_launch(void* const* d_in, const int* in_sizes, int n_in,
                              void* d_out, int out_size, void* d_ws, size_t ws_size,
                              hipStream_t stream){
  const float* x    =(const float*)d_in[0];
  const int*   ei   =(const int*)d_in[1];
  const int*   prodi=(const int*)d_in[2];
  const int*   linei=(const int*)d_in[3];
  const int*   loci =(const int*)d_in[4];
  const float* ew   =(const float*)d_in[5];
  const float* eb   =(const float*)d_in[6];
  const float* lng  =(const float*)d_in[7];
  const float* lnb  =(const float*)d_in[8];
  const float* wrel =(const float*)d_in[9];
  const float* brel =(const float*)d_in[10];
  const float* wroot=(const float*)d_in[11];
  const float* pw   =(const float*)d_in[12];
  const float* pb   =(const float*)d_in[13];
  const float* fw   =(const float*)d_in[14];
  const float* fb   =(const float*)d_in[15];
  const float* gm   =(const float*)d_in[16];
  const float* lm   =(const float*)d_in[17];

  char* ws=(char*)d_ws;
  unsigned short* hnA =(unsigned short*)ws;                        // NT*64 bf16 (46.1 MB)
  unsigned short* hnB =hnA + (size_t)NT_*64;                       // NT*64 bf16 (46.1 MB)
  unsigned short* wcat=hnB + (size_t)NT_*64;                       // 32768 bf16
  float* pT =(float*)(wcat + 32768);                               // G*B
  float* fT =pT + (size_t)G_*B_;                                   // F*B
  float* mdT=fT + (size_t)F_*B_;                                   // L*64
  int* cnt =(int*)(mdT + (size_t)L_*64);
  int* off = cnt + N_;
  int* cur = off + (N_+1);
  int* srcs= cur + N_;
  int* ecnt= srcs + EG_;
  int4* ent=(int4*)(((size_t)(ecnt+1)+15)&~(size_t)15);

  float* outp =(float*)d_out;
  float* outf =outp + (size_t)B_*G_;
  float* outmd=outf + (size_t)B_*F_;

  k_init<<<512,256,0,stream>>>(cnt,mdT,ecnt,wrel,wroot,wcat);
  k_hist<<<64,256,0,stream>>>(ei,cnt);
  k_scan<<<1,1024,0,stream>>>(cnt,off,cur);
  k_scatter<<<64,256,0,stream>>>(ei,cur,srcs);
  k_md_sparsify<<<1024,256,0,stream>>>(gm,lm,ecnt,ent);
  k_enc<<<NT_/32,256,0,stream>>>(x,hnA,ew,eb,lng,lnb);
  for(int i=0;i<4;i++){
    const unsigned short* hs=(i&1)?hnB:hnA;
    unsigned short* hd=(i&1)?hnA:hnB;
    k_layer<<<B_*(N_/64),256,0,stream>>>(hs,hd,off,srcs,wcat+(size_t)i*8192,
        brel+(size_t)i*64,lng,lnb,(i<3)?1:0);
  }
  // after 4 layers (A->B->A->B->A) result is in hnA
  k_readout<<<(B_*G_)/256,256,0,stream>>>(hnA,prodi,pw,pb,outp,pT,B_*G_,G_);
  k_readout<<<(B_*F_)/256,256,0,stream>>>(hnA,linei,fw,fb,outf,fT,B_*F_,F_);
  k_md_scatter<<<MAXE_/4,256,0,stream>>>(ent,ecnt,pT,fT,mdT);
  k_md_final<<<(B_*L_)/256,256,0,stream>>>(x,loci,mdT,outmd);
}